// Round 8
// baseline (236.070 us; speedup 1.0000x reference)
//
#include <hip/hip_runtime.h>
#include <hip/hip_bf16.h>
#include <stdint.h>

#define BATCH 4096
#define KGRP  8
#define BLK   1024
#define TOTAL 8192

typedef __attribute__((ext_vector_type(8))) short short8;
typedef __attribute__((ext_vector_type(4))) float f32x4;

#define AS1 __attribute__((address_space(1)))
#define AS3 __attribute__((address_space(3)))

// LDS map (149504 B total, 1 block/CU):
//   [0, 24576)       K-buf0: A[128][32]bf16 @0 (8K) + B[256][32]bf16 @8192 (16K)
//   [24576, 49152)   K-buf1
//   [49152, 114688)  x-stage region: 64 rows x 256 f32 (one half-tile of x)
//   [114688, 149504) epilogue bounce: 8 waves x 4352
#define LDS_XOFF   49152u
#define LDS_EBOFF  114688u

// ---------- helpers ----------

__device__ __forceinline__ unsigned short f2bf(float f) {
    union { float f; uint32_t u; } c; c.f = f;
    uint32_t u = c.u;
    u += 0x7fffu + ((u >> 16) & 1u);   // round-to-nearest-even
    return (unsigned short)(u >> 16);
}

__device__ __forceinline__ float fast_tanh(float x) {
    float e = __expf(2.0f * x);
    return 1.0f - 2.0f / (e + 1.0f);
}

__device__ __forceinline__ void gload16(const unsigned short* src, char* dst) {
    __builtin_amdgcn_global_load_lds((const AS1 uint32_t*)src, (AS3 uint32_t*)dst, 16, 0, 0);
}
__device__ __forceinline__ void gload4(const float* src, char* dst) {
    __builtin_amdgcn_global_load_lds((const AS1 uint32_t*)src, (AS3 uint32_t*)dst, 4, 0, 0);
}

template<int N> __device__ __forceinline__ void waitvm() {
    if constexpr (N == 0)       asm volatile("s_waitcnt vmcnt(0)" ::: "memory");
    else if constexpr (N == 2)  asm volatile("s_waitcnt vmcnt(2)" ::: "memory");
    else if constexpr (N == 4)  asm volatile("s_waitcnt vmcnt(4)" ::: "memory");
    else if constexpr (N == 6)  asm volatile("s_waitcnt vmcnt(6)" ::: "memory");
    else if constexpr (N == 14) asm volatile("s_waitcnt vmcnt(14)" ::: "memory");
}
__device__ __forceinline__ void waitlgkm0() {
    asm volatile("s_waitcnt lgkmcnt(0)" ::: "memory");
}

// ---------- tiny prep: W f32 -> bf16 (16 MB out; ~8 us) ----------

__global__ void k_wcast(const float4* __restrict__ W, ushort4* __restrict__ Wb) {
    const int n4 = KGRP * BLK * BLK / 4;
    for (int i = blockIdx.x * 256 + threadIdx.x; i < n4; i += 1024 * 256) {
        float4 f = W[i];
        ushort4 o;
        o.x = f2bf(f.x); o.y = f2bf(f.y); o.z = f2bf(f.z); o.w = f2bf(f.w);
        Wb[i] = o;
    }
}

// ---------- K-tile body ----------
// Swizzle (both sides): phys = log ^ (((log>>7)&3)<<4) on 64B rows (r4/r6-verified).
// A is reg-staged (v f32 -> tanh -> bf16 -> swizzled ds_write); B via gload_lds with
// pre-swizzled source (r7-verified). vmcnt by conservative region counting: to
// guarantee op X done, wait vmcnt(K) where K = count of ALL VMEM issued after X's
// phase (xd=2, va=2, B=2 per tile; flush stores=8). sched_barrier(0) pins phases.

template<bool HASE, bool WRA, bool ISSV, bool ISSB, int W>
__device__ __forceinline__ void body(int kt, char* ldsp,
                                     const float* vsrcT, const unsigned short* BsrcT,
                                     const float* xsrcP,
                                     float4& va0, float4& va1,
                                     uint32_t awOff, uint32_t aBase, uint32_t bBase,
                                     uint32_t sdstB, int w, int lane,
                                     f32x4 (*acc)[4]) {
    const uint32_t cur = (uint32_t)(kt & 1) * 24576u;
    const uint32_t oth = cur ^ 24576u;
    const char* Lb = ldsp + cur;

    // ---- ph0 ----
    if constexpr (WRA) {   // write A(kt+1) into oth (last read at kt-1; boundary barrier passed)
        short8 p;
        p[0] = (short)f2bf(fast_tanh(va0.x)); p[1] = (short)f2bf(fast_tanh(va0.y));
        p[2] = (short)f2bf(fast_tanh(va0.z)); p[3] = (short)f2bf(fast_tanh(va0.w));
        p[4] = (short)f2bf(fast_tanh(va1.x)); p[5] = (short)f2bf(fast_tanh(va1.y));
        p[6] = (short)f2bf(fast_tanh(va1.z)); p[7] = (short)f2bf(fast_tanh(va1.w));
        *(short8*)(ldsp + oth + awOff) = p;
    }
    short8 bfr[4], am[2];
#pragma unroll
    for (int n = 0; n < 4; ++n)
        bfr[n] = *(const short8*)(Lb + bBase + n * 1024);
#pragma unroll
    for (int i = 0; i < 2; ++i)
        am[i] = *(const short8*)(Lb + aBase + i * 2048);
    if constexpr (HASE) {  // stage x slice (2 x width-4 DMA per wave per tile)
        const float* xs = xsrcP + (size_t)(kt >> 4) * 64 * TOTAL;
#pragma unroll
        for (int j = 0; j < 2; ++j) {
            const int ci = (kt & 15) * 16 + w * 2 + j;
            gload4(xs + (size_t)(ci >> 2) * TOTAL + (ci & 3) * 64 + lane,
                   ldsp + LDS_XOFF + (uint32_t)ci * 256u);
        }
    }
    if constexpr (ISSV) {  // issue v loads for A(kt+2)
        va0 = *(const float4*)(vsrcT + (size_t)(kt + 2) * 32);
        va1 = *(const float4*)(vsrcT + (size_t)(kt + 2) * 32 + 4);
    }
#pragma unroll
    for (int i = 0; i < 2; ++i)
#pragma unroll
        for (int n = 0; n < 4; ++n)
            acc[i][n] = __builtin_amdgcn_mfma_f32_16x16x32_bf16(am[i], bfr[n], acc[i][n], 0, 0, 0);
    __builtin_amdgcn_s_barrier();
    __builtin_amdgcn_sched_barrier(0);

    // ---- ph1 ----
#pragma unroll
    for (int i = 0; i < 2; ++i)
        am[i] = *(const short8*)(Lb + aBase + (2 + i) * 2048);
    if constexpr (ISSB) {  // DMA B(kt+2) into cur's B region (consumed at ph0; mid-barrier passed)
        gload16(BsrcT + (size_t)(kt + 2) * 32, ldsp + cur + 8192u + sdstB);
        gload16(BsrcT + (size_t)128 * BLK + (size_t)(kt + 2) * 32, ldsp + cur + 16384u + sdstB);
    }
#pragma unroll
    for (int i = 0; i < 2; ++i)
#pragma unroll
        for (int n = 0; n < 4; ++n)
            acc[2 + i][n] = __builtin_amdgcn_mfma_f32_16x16x32_bf16(am[i], bfr[n], acc[2 + i][n], 0, 0, 0);
    waitlgkm0();
    if constexpr (W >= 0) waitvm<W>();
    __builtin_amdgcn_s_barrier();
    __builtin_amdgcn_sched_barrier(0);
}

// ---------- flush: drain accP half H (m = 2H, 2H+1) with x from LDS ----------
// acc C/D mapping (m89/m91): col = lane&15, row(frag) = (lane>>4)*4 + j.
// Row org: frag m covers tile rows m*32 + wr*16 + 0..15.

template<int H>
__device__ __forceinline__ void flushhalf(f32x4 (*accP)[4], char* ldsp,
                                          int w, int lane, int wr, int wc,
                                          float4 bias4, float* out, size_t outRowBase) {
    char* eb = ldsp + LDS_EBOFF + (uint32_t)w * 4352u;
    const char* xl = ldsp + LDS_XOFF;
    const int q = lane >> 4, cl = lane & 15;
#pragma unroll
    for (int mm = 0; mm < 2; ++mm) {
        const int mabs = 2 * H + mm;
#pragma unroll
        for (int n = 0; n < 4; ++n)
#pragma unroll
            for (int j = 0; j < 4; ++j)
                *(float*)(eb + (q * 4 + j) * 272 + (n * 16 + cl) * 4) = accP[mabs][n][j];
        waitlgkm0();
        __builtin_amdgcn_sched_barrier(0);
#pragma unroll
        for (int i = 0; i < 4; ++i) {
            const int lr = mm * 32 + wr * 16 + q + 4 * i;
            f32x4 vv = *(const f32x4*)(eb + (q + 4 * i) * 272 + cl * 16);
            f32x4 xv = *(const f32x4*)(xl + lr * 1024 + wc * 256 + cl * 16);
            const size_t idx = outRowBase + (size_t)lr * TOTAL + wc * 64 + cl * 4;
            float4 o;
            o.x = xv[0] + bias4.x + vv[0];
            o.y = xv[1] + bias4.y + vv[1];
            o.z = xv[2] + bias4.z + vv[2];
            o.w = xv[3] + bias4.w + vv[3];
            *(float4*)&out[idx] = o;
        }
        waitlgkm0();
        __builtin_amdgcn_sched_barrier(0);
    }
}

// ---------- one sub-tile: full K loop (32 tiles), with E(s-1) interleaved ----------

template<bool HASE>
__device__ __forceinline__ void subtile(int mt, int mtP, char* ldsp,
                                        const float* v, const unsigned short* Wb,
                                        const float* x, float* out,
                                        int g, int gout, int ntile,
                                        int tid, int w, int lane, int wr, int wc,
                                        uint32_t awOff, uint32_t aBase, uint32_t bBase,
                                        uint32_t sdstB, const unsigned short* BsrcT,
                                        float4 bias4,
                                        f32x4 (*accC)[4], f32x4 (*accP)[4]) {
#pragma unroll
    for (int m = 0; m < 4; ++m)
#pragma unroll
        for (int n = 0; n < 4; ++n) accC[m][n] = (f32x4){0.f, 0.f, 0.f, 0.f};

    const float* vsrcT = v + (size_t)(mt * 128 + (tid >> 2)) * TOTAL + (size_t)g * BLK + (tid & 3) * 8;
    const float* xsrcP = x + (size_t)(mtP * 128) * TOTAL + (size_t)gout * BLK + ntile * 256;
    const size_t outB0 = (size_t)(mtP * 128) * TOTAL + (size_t)gout * BLK + ntile * 256;
    float4 va0, va1;

    // prologue: A(0) direct, va<-v(1), B(0),B(1) DMA; full drain.
    {
        float4 t0a = *(const float4*)(vsrcT);
        float4 t0b = *(const float4*)(vsrcT + 4);
        va0 = *(const float4*)(vsrcT + 32);
        va1 = *(const float4*)(vsrcT + 36);
        gload16(BsrcT, ldsp + 8192u + sdstB);
        gload16(BsrcT + (size_t)128 * BLK, ldsp + 16384u + sdstB);
        gload16(BsrcT + 32, ldsp + 24576u + 8192u + sdstB);
        gload16(BsrcT + (size_t)128 * BLK + 32, ldsp + 24576u + 16384u + sdstB);
        short8 p;
        p[0] = (short)f2bf(fast_tanh(t0a.x)); p[1] = (short)f2bf(fast_tanh(t0a.y));
        p[2] = (short)f2bf(fast_tanh(t0a.z)); p[3] = (short)f2bf(fast_tanh(t0a.w));
        p[4] = (short)f2bf(fast_tanh(t0b.x)); p[5] = (short)f2bf(fast_tanh(t0b.y));
        p[6] = (short)f2bf(fast_tanh(t0b.z)); p[7] = (short)f2bf(fast_tanh(t0b.w));
        *(short8*)(ldsp + awOff) = p;
        waitlgkm0();
        waitvm<0>();
        __builtin_amdgcn_s_barrier();
        __builtin_amdgcn_sched_barrier(0);
    }

#pragma unroll 1
    for (int kt = 0; kt < 15; ++kt)
        body<HASE, true, true, true, (HASE ? 6 : 4)>(kt, ldsp, vsrcT, BsrcT, xsrcP,
            va0, va1, awOff, aBase, bBase, sdstB, w, lane, accC);
    // kt=15: stricter wait (drain xd half0) when flushing
    body<HASE, true, true, true, (HASE ? 2 : 4)>(15, ldsp, vsrcT, BsrcT, xsrcP,
        va0, va1, awOff, aBase, bBase, sdstB, w, lane, accC);
    if constexpr (HASE) {
        flushhalf<0>(accP, ldsp, w, lane, wr, wc, bias4, out, outB0);
        waitlgkm0();
        __builtin_amdgcn_s_barrier();
        __builtin_amdgcn_sched_barrier(0);
    }
    // kt=16: W accounts for 8 flush stores still possibly in flight
    body<HASE, true, true, true, (HASE ? 14 : 4)>(16, ldsp, vsrcT, BsrcT, xsrcP,
        va0, va1, awOff, aBase, bBase, sdstB, w, lane, accC);
#pragma unroll 1
    for (int kt = 17; kt < 30; ++kt)
        body<HASE, true, true, true, (HASE ? 6 : 4)>(kt, ldsp, vsrcT, BsrcT, xsrcP,
            va0, va1, awOff, aBase, bBase, sdstB, w, lane, accC);
    body<HASE, true, false, false, (HASE ? 2 : 0)>(30, ldsp, vsrcT, BsrcT, xsrcP,
        va0, va1, awOff, aBase, bBase, sdstB, w, lane, accC);
    body<HASE, false, false, false, (HASE ? 0 : -1)>(31, ldsp, vsrcT, BsrcT, xsrcP,
        va0, va1, awOff, aBase, bBase, sdstB, w, lane, accC);
    if constexpr (HASE) {
        flushhalf<1>(accP, ldsp, w, lane, wr, wc, bias4, out,
                     outB0 + (size_t)64 * TOTAL);
        waitlgkm0();
        __builtin_amdgcn_s_barrier();
        __builtin_amdgcn_sched_barrier(0);
    }
}

// ---------- main GEMM: 256 blocks x 512 thr, 4 output tiles per block ----------

__global__ __launch_bounds__(512, 2)
void k_gemm(const float* __restrict__ v, const unsigned short* __restrict__ Wb,
            const float* __restrict__ x, const float* __restrict__ bias,
            float* __restrict__ out) {
    __shared__ __attribute__((aligned(1024))) char lds[149504];
    char* ldsp = lds;

    const int bid   = blockIdx.x;              // 0..255
    const int g     = bid & 7;                 // XCD affinity: Wb[g] L2-resident
    const int slot  = bid >> 3;                // 0..31
    const int ntile = slot & 3;                // 0..3
    const int mq    = slot >> 2;               // 0..7 -> mtiles mq*4..mq*4+3
    const int gout  = (g + 1) & 7;

    const int tid  = threadIdx.x;
    const int lane = tid & 63;
    const int w    = tid >> 6;                 // 0..7
    const int wr   = w >> 2;                   // 0..1
    const int wc   = w & 3;                    // 0..3

    // ds_read swizzled column (r7-verified): kc = ((lane>>4) ^ ((lane>>1)&3)) << 4
    const uint32_t kc    = ((uint32_t)((lane >> 4) ^ ((lane >> 1) & 3))) << 4;
    // A frag m covers rows m*32 + wr*16 + (lane&15): base + m*2048
    const uint32_t aBase = (uint32_t)(wr * 16 + (lane & 15)) * 64u + kc;
    const uint32_t bBase = 8192u + (uint32_t)(wc * 64 + (lane & 15)) * 64u + kc;
    // A ds_write: thread t -> row t>>2, logical slot t&3, phys slot ^= (row>>1)&3
    const uint32_t awOff = (uint32_t)((tid >> 2) * 64) +
                           ((uint32_t)((tid & 3) ^ ((tid >> 3) & 3)) << 4);
    // B staging source pre-swizzle (r7-verified)
    const int sColB = ((lane & 3) ^ ((lane >> 3) & 3)) << 3;
    const unsigned short* BsrcT = Wb + (size_t)g * BLK * BLK
                                     + (size_t)(ntile * 256 + w * 16 + (lane >> 2)) * BLK + sColB;
    const uint32_t sdstB = (uint32_t)(w << 10);

    const float4 bias4 = *(const float4*)&bias[g * BLK + ntile * 256 + wc * 64 + (lane & 15) * 4];

    f32x4 acc0[4][4], acc1[4][4];

    subtile<false>(mq * 4 + 0, 0,          ldsp, v, Wb, x, out, g, gout, ntile,
                   tid, w, lane, wr, wc, awOff, aBase, bBase, sdstB, BsrcT, bias4, acc0, acc1);
    subtile<true >(mq * 4 + 1, mq * 4 + 0, ldsp, v, Wb, x, out, g, gout, ntile,
                   tid, w, lane, wr, wc, awOff, aBase, bBase, sdstB, BsrcT, bias4, acc1, acc0);
    subtile<true >(mq * 4 + 2, mq * 4 + 1, ldsp, v, Wb, x, out, g, gout, ntile,
                   tid, w, lane, wr, wc, awOff, aBase, bBase, sdstB, BsrcT, bias4, acc0, acc1);
    subtile<true >(mq * 4 + 3, mq * 4 + 2, ldsp, v, Wb, x, out, g, gout, ntile,
                   tid, w, lane, wr, wc, awOff, aBase, bBase, sdstB, BsrcT, bias4, acc1, acc0);

    // ---- final epilogue for acc(3) (direct x reads; bounce region; r7 pattern) ----
    {
        const int mt3 = mq * 4 + 3;
        char* eb = ldsp + LDS_EBOFF + (uint32_t)w * 4352u;
        const int q = lane >> 4, cl = lane & 15;
        const size_t base0 = (size_t)(mt3 * 128) * TOTAL + (size_t)gout * BLK + ntile * 256;
#pragma unroll
        for (int m = 0; m < 4; ++m) {
#pragma unroll
            for (int n = 0; n < 4; ++n)
#pragma unroll
                for (int j = 0; j < 4; ++j)
                    *(float*)(eb + (q * 4 + j) * 272 + (n * 16 + cl) * 4) = acc1[m][n][j];
            waitlgkm0();
            __builtin_amdgcn_sched_barrier(0);
#pragma unroll
            for (int i = 0; i < 4; ++i) {
                const int r = m * 32 + wr * 16 + q + 4 * i;
                f32x4 vv = *(const f32x4*)(eb + (q + 4 * i) * 272 + cl * 16);
                const size_t idx = base0 + (size_t)r * TOTAL + wc * 64 + cl * 4;
                const float4 xv = *(const float4*)&x[idx];
                float4 o;
                o.x = xv.x + bias4.x + vv[0];
                o.y = xv.y + bias4.y + vv[1];
                o.z = xv.z + bias4.z + vv[2];
                o.w = xv.w + bias4.w + vv[3];
                *(float4*)&out[idx] = o;
            }
            waitlgkm0();
            __builtin_amdgcn_sched_barrier(0);
        }
    }
}

// ---------- fallback (ws too small): correct but slow ----------

__global__ void k_naive(const float* __restrict__ x, const float* __restrict__ v,
                        const float* __restrict__ W, const float* __restrict__ b,
                        float* __restrict__ out) {
    __shared__ float hv[BLK];
    const int bid = blockIdx.x;
    const int quarter = bid & 3;
    const int g = (bid >> 2) & 7;
    const int row = bid >> 5;
    for (int i = threadIdx.x; i < BLK; i += 256)
        hv[i] = tanhf(v[(size_t)row * TOTAL + g * BLK + i]);
    __syncthreads();
    const int o = quarter * 256 + threadIdx.x;
    const float* wrow = W + ((size_t)g * BLK + o) * BLK;
    float s = 0.f;
    for (int i = 0; i < BLK; ++i) s += hv[i] * wrow[i];
    const size_t oi = (size_t)row * TOTAL + (size_t)((g + 1) & 7) * BLK + o;
    out[oi] = x[oi] + b[g * BLK + o] + s;
}

// ---------- launch ----------

extern "C" void kernel_launch(void* const* d_in, const int* in_sizes, int n_in,
                              void* d_out, int out_size, void* d_ws, size_t ws_size,
                              hipStream_t stream) {
    const float* x = (const float*)d_in[0];
    const float* v = (const float*)d_in[1];
    const float* W = (const float*)d_in[2];
    const float* b = (const float*)d_in[3];
    float* out = (float*)d_out;

    const size_t needW = (size_t)KGRP * BLK * BLK * sizeof(unsigned short);   // 16 MB

    if (ws_size >= needW) {
        unsigned short* Wb = (unsigned short*)d_ws;
        k_wcast<<<1024, 256, 0, stream>>>((const float4*)W, (ushort4*)Wb);
        k_gemm<<<256, 512, 0, stream>>>(v, Wb, x, b, out);
    } else {
        k_naive<<<BATCH * KGRP * 4, 256, 0, stream>>>(x, v, W, b, out);
    }
}

// Round 9
// 157.703 us; speedup vs baseline: 1.4969x; 1.4969x over previous
//
#include <hip/hip_runtime.h>
#include <hip/hip_bf16.h>
#include <stdint.h>

#define BATCH 4096
#define KGRP  8
#define BLK   1024
#define TOTAL 8192

typedef __attribute__((ext_vector_type(8))) short short8;
typedef __attribute__((ext_vector_type(4))) float f32x4;

#define AS1 __attribute__((address_space(1)))
#define AS3 __attribute__((address_space(3)))

// ---------- helpers ----------

__device__ __forceinline__ unsigned short f2bf(float f) {
    union { float f; uint32_t u; } c; c.f = f;
    uint32_t u = c.u;
    u += 0x7fffu + ((u >> 16) & 1u);   // round-to-nearest-even
    return (unsigned short)(u >> 16);
}

__device__ __forceinline__ float fast_tanh(float x) {
    float e = __expf(2.0f * x);
    return 1.0f - 2.0f / (e + 1.0f);
}

// ---------- pass 1 (merged): tanh(v) -> bf16 H, W -> bf16 Wb ----------

__global__ void k_prep(const float4* __restrict__ v, ushort4* __restrict__ H,
                       const float4* __restrict__ W, ushort4* __restrict__ Wb) {
    const int b = blockIdx.x;
    if (b < 2048) {
        const int n4 = BATCH * TOTAL / 4;
        for (int i = b * 256 + threadIdx.x; i < n4; i += 2048 * 256) {
            float4 f = v[i];
            ushort4 o;
            o.x = f2bf(fast_tanh(f.x)); o.y = f2bf(fast_tanh(f.y));
            o.z = f2bf(fast_tanh(f.z)); o.w = f2bf(fast_tanh(f.w));
            H[i] = o;
        }
    } else {
        const int n4 = KGRP * BLK * BLK / 4;
        for (int i = (b - 2048) * 256 + threadIdx.x; i < n4; i += 512 * 256) {
            float4 f = W[i];
            ushort4 o;
            o.x = f2bf(f.x); o.y = f2bf(f.y); o.z = f2bf(f.z); o.w = f2bf(f.w);
            Wb[i] = o;
        }
    }
}

// ---------- pass 2: grouped GEMM, 128x256 tile, BK=32, 8 waves, TRIPLE buffer ----------
// C[m][n] = sum_k H[m][k] * W[n][k]; epilogue fuses x + bias (LDS-bounce float4).
//
// ROUND-9 CHANGE: remove ALL intra-tile barriers / explicit lgkm waits; let the
// compiler's fine-grained lgkmcnt interleave the 8 ds_reads with the 16 MFMAs
// (wave-skew then overlaps LDS and MFMA pipes across waves). Write hazards are
// eliminated by TRIPLE buffering (3 x 24 KiB = 72 KiB < 80 KiB -> still 2
// blocks/CU): during tile T, stage (A,B)(T+2) into buf[(T+2)%3] whose last
// readers (tile T-1) all passed the end-of-(T-1) barrier; its consumers are 2
// tiles away (~4800 cy >> 900 cy HBM latency). ONE barrier per tile, preceded
// by counted vmcnt(3): guards stage(T+1) (issued during T-1), allowing
// stage(T+2)'s 3 loads to stay in flight. Tail peeled exactly (r3 lesson):
// kt=30 no stage -> vmcnt(0); kt=31 no stage, no boundary.
//
// Per-buffer layout: A[128][32]bf16 @0 (8K) + B[256][32]bf16 @8192 (16K).
// Swizzle (both-sides, rule #21, r4/r6/r7-verified on 64B rows):
//   phys = log ^ (((log>>7)&3)<<4); ds_read col kc = ((lane>>4)^((lane>>1)&3))<<4;
//   staging source pre-swizzle sCol = ((lane&3)^((lane>>3)&3))<<3.

__device__ __forceinline__ void gload16(const unsigned short* src, char* dst) {
    __builtin_amdgcn_global_load_lds((const AS1 uint32_t*)src, (AS3 uint32_t*)dst, 16, 0, 0);
}

template<int N> __device__ __forceinline__ void waitvm() {
    if constexpr (N == 0)      asm volatile("s_waitcnt vmcnt(0)" ::: "memory");
    else if constexpr (N == 3) asm volatile("s_waitcnt vmcnt(3)" ::: "memory");
}

template<bool ST, int W, int CUR>
__device__ __forceinline__ void tile3(int kt, char* ldsp,
                                      uint32_t aRowB, uint32_t bRowB,
                                      f32x4 (*acc)[4],
                                      const unsigned short* Asrc, const unsigned short* Bsrc,
                                      uint32_t sdst) {
    constexpr uint32_t bufb = (uint32_t)(CUR * 24576);
    constexpr uint32_t stgb = (uint32_t)(((CUR + 2) % 3) * 24576);
    const char* Lb = ldsp + bufb;

    // stage tile kt+2 into buf[(kt+2)%3] (region idle since end-of-(kt-1) barrier)
    if constexpr (ST) {
        gload16(Asrc + (size_t)(kt + 2) * 32, ldsp + stgb + sdst);
        gload16(Bsrc + (size_t)(kt + 2) * 32, ldsp + stgb + 8192u + sdst);
        gload16(Bsrc + (size_t)128 * BLK + (size_t)(kt + 2) * 32, ldsp + stgb + 16384u + sdst);
    }

    // 8 ds_reads + 16 MFMA, compiler-scheduled (fine-grained lgkmcnt, m97-verified)
    short8 bfr[4], am0[2], am1[2];
#pragma unroll
    for (int n = 0; n < 4; ++n)
        bfr[n] = *(const short8*)(Lb + bRowB + n * 1024);
#pragma unroll
    for (int i = 0; i < 2; ++i)
        am0[i] = *(const short8*)(Lb + aRowB + i * 1024);
#pragma unroll
    for (int i = 0; i < 2; ++i)
        am1[i] = *(const short8*)(Lb + aRowB + (2 + i) * 1024);

    __builtin_amdgcn_s_setprio(1);
#pragma unroll
    for (int i = 0; i < 2; ++i)
#pragma unroll
        for (int n = 0; n < 4; ++n)
            acc[i][n] = __builtin_amdgcn_mfma_f32_16x16x32_bf16(am0[i], bfr[n], acc[i][n], 0, 0, 0);
#pragma unroll
    for (int i = 0; i < 2; ++i)
#pragma unroll
        for (int n = 0; n < 4; ++n)
            acc[2 + i][n] = __builtin_amdgcn_mfma_f32_16x16x32_bf16(am1[i], bfr[n], acc[2 + i][n], 0, 0, 0);
    __builtin_amdgcn_s_setprio(0);

    // tile boundary: buf[(kt+1)%3] must be ready (stage issued during kt-1).
    if constexpr (W >= 0) {
        waitvm<W>();
        __builtin_amdgcn_s_barrier();
        __builtin_amdgcn_sched_barrier(0);
    }
}

__global__ __launch_bounds__(512, 4)
void k_gemm(const unsigned short* __restrict__ H, const unsigned short* __restrict__ Wb,
            const float* __restrict__ x, const float* __restrict__ bias,
            float* __restrict__ out) {
    __shared__ __attribute__((aligned(1024))) char lds[73728];   // 3 x 24576; bounce reuses
    char* ldsp = lds;

    // T1: XCD swizzle. bid&7 == XCD; each XCD owns one group -> Wb[g] (2MB) L2-resident.
    const int bid   = blockIdx.x;              // 0..1023
    const int g     = bid & 7;
    const int slot  = bid >> 3;                // 0..127
    const int mtile = slot >> 2;               // 0..31
    const int ntile = slot & 3;                // 0..3

    const int tid  = threadIdx.x;
    const int lane = tid & 63;
    const int w    = tid >> 6;                 // 0..7
    const int wr   = w >> 2;                   // 0..1  (M)
    const int wc   = w & 3;                    // 0..3  (N)

    // ds_read swizzled column (r7-verified)
    const uint32_t kc    = ((uint32_t)((lane >> 4) ^ ((lane >> 1) & 3))) << 4;
    const uint32_t aRowB = (uint32_t)(wr * 64 + (lane & 15)) * 64u + kc;           // A @0
    const uint32_t bRowB = 8192u + (uint32_t)(wc * 64 + (lane & 15)) * 64u + kc;   // B @8K

    // staging source pre-swizzle (r7-verified)
    const int sCol = ((lane & 3) ^ ((lane >> 3) & 3)) << 3;
    const unsigned short* Asrc = H + (size_t)(mtile * 128 + w * 16 + (lane >> 2)) * TOTAL
                                   + (size_t)g * BLK + sCol;
    const unsigned short* Bsrc = Wb + (size_t)g * BLK * BLK
                                    + (size_t)(ntile * 256 + w * 16 + (lane >> 2)) * BLK + sCol;
    const uint32_t sdst = (uint32_t)(w << 10);     // wave-uniform; HW adds lane*16

    f32x4 acc[4][4];
#pragma unroll
    for (int m = 0; m < 4; ++m)
#pragma unroll
        for (int n = 0; n < 4; ++n) acc[m][n] = (f32x4){0.f, 0.f, 0.f, 0.f};

    // prologue: stage tile 0 -> buf0, tile 1 -> buf1; guard tile 0 (newer = 3 loads)
    gload16(Asrc + 0, ldsp + 0u + sdst);
    gload16(Bsrc + 0, ldsp + 8192u + sdst);
    gload16(Bsrc + (size_t)128 * BLK, ldsp + 16384u + sdst);
    gload16(Asrc + 32, ldsp + 24576u + sdst);
    gload16(Bsrc + 32, ldsp + 24576u + 8192u + sdst);
    gload16(Bsrc + (size_t)128 * BLK + 32, ldsp + 24576u + 16384u + sdst);
    waitvm<3>();
    __builtin_amdgcn_s_barrier();
    __builtin_amdgcn_sched_barrier(0);

#pragma unroll 1
    for (int kt = 0; kt < 30; kt += 3) {
        tile3<true, 3, 0>(kt,     ldsp, aRowB, bRowB, acc, Asrc, Bsrc, sdst);
        tile3<true, 3, 1>(kt + 1, ldsp, aRowB, bRowB, acc, Asrc, Bsrc, sdst);
        tile3<true, 3, 2>(kt + 2, ldsp, aRowB, bRowB, acc, Asrc, Bsrc, sdst);
    }
    tile3<false, 0, 0>(30, ldsp, aRowB, bRowB, acc, Asrc, Bsrc, sdst);   // guard stage(31)
    tile3<false, -1, 1>(31, ldsp, aRowB, bRowB, acc, Asrc, Bsrc, sdst);

    // all waves done reading K-loop buffers before the bounce reuses them
    __builtin_amdgcn_s_barrier();

    // ---------------- epilogue: out = x + bias + acc (r7-verified pattern) ----------
    // acc C/D mapping (m89/m91): col = lane&15, row = (lane>>4)*4 + j.
    const int gout = (g + 1) & 7;
    const int q    = lane >> 4;                 // 0..3
    const int cl   = lane & 15;                 // 0..15
    const int row0 = mtile * 128 + wr * 64;
    const int col0 = ntile * 256 + wc * 64;     // within group
    char* eb = ldsp + (uint32_t)w * 4352u;
    const float4 bias4 = *(const float4*)&bias[g * BLK + col0 + cl * 4];

#pragma unroll
    for (int m = 0; m < 4; ++m) {
#pragma unroll
        for (int n = 0; n < 4; ++n)
#pragma unroll
            for (int j = 0; j < 4; ++j)
                *(float*)(eb + (q * 4 + j) * 272 + (n * 16 + cl) * 4) = acc[m][n][j];
        asm volatile("s_waitcnt lgkmcnt(0)" ::: "memory");
        __builtin_amdgcn_sched_barrier(0);
#pragma unroll
        for (int i = 0; i < 4; ++i) {
            f32x4 vv = *(const f32x4*)(eb + (q + 4 * i) * 272 + cl * 16);
            const int r = row0 + m * 16 + q + 4 * i;
            const size_t idx = (size_t)r * TOTAL + (size_t)gout * BLK + col0 + cl * 4;
            const float4 xv = *(const float4*)&x[idx];
            float4 o;
            o.x = xv.x + bias4.x + vv[0];
            o.y = xv.y + bias4.y + vv[1];
            o.z = xv.z + bias4.z + vv[2];
            o.w = xv.w + bias4.w + vv[3];
            *(float4*)&out[idx] = o;
        }
        asm volatile("s_waitcnt lgkmcnt(0)" ::: "memory");
        __builtin_amdgcn_sched_barrier(0);
    }
}

// ---------- fallback (ws too small): correct but slow ----------

__global__ void k_naive(const float* __restrict__ x, const float* __restrict__ v,
                        const float* __restrict__ W, const float* __restrict__ b,
                        float* __restrict__ out) {
    __shared__ float hv[BLK];
    const int bid = blockIdx.x;
    const int quarter = bid & 3;
    const int g = (bid >> 2) & 7;
    const int row = bid >> 5;
    for (int i = threadIdx.x; i < BLK; i += 256)
        hv[i] = tanhf(v[(size_t)row * TOTAL + g * BLK + i]);
    __syncthreads();
    const int o = quarter * 256 + threadIdx.x;
    const float* wrow = W + ((size_t)g * BLK + o) * BLK;
    float s = 0.f;
    for (int i = 0; i < BLK; ++i) s += hv[i] * wrow[i];
    const size_t oi = (size_t)row * TOTAL + (size_t)((g + 1) & 7) * BLK + o;
    out[oi] = x[oi] + b[g * BLK + o] + s;
}

// ---------- launch ----------

extern "C" void kernel_launch(void* const* d_in, const int* in_sizes, int n_in,
                              void* d_out, int out_size, void* d_ws, size_t ws_size,
                              hipStream_t stream) {
    const float* x = (const float*)d_in[0];
    const float* v = (const float*)d_in[1];
    const float* W = (const float*)d_in[2];
    const float* b = (const float*)d_in[3];
    float* out = (float*)d_out;

    const size_t needH = (size_t)BATCH * TOTAL * sizeof(unsigned short);      // 64 MB
    const size_t needW = (size_t)KGRP * BLK * BLK * sizeof(unsigned short);   // 16 MB

    if (ws_size >= needH + needW) {
        unsigned short* H  = (unsigned short*)d_ws;
        unsigned short* Wb = (unsigned short*)((char*)d_ws + needH);
        k_prep<<<2560, 256, 0, stream>>>((const float4*)v, (ushort4*)H,
                                         (const float4*)W, (ushort4*)Wb);
        k_gemm<<<1024, 512, 0, stream>>>(H, Wb, x, b, out);
    } else {
        k_naive<<<BATCH * KGRP * 4, 256, 0, stream>>>(x, v, W, b, out);
    }
}